// Round 6
// baseline (589.806 us; speedup 1.0000x reference)
//
#include <hip/hip_runtime.h>
#include <stdint.h>

constexpr int B = 8, N = 8192, S = 2048, D1 = 128, D2 = 256;
constexpr int CIN = 384, CMID = 256, COUT = 256;

typedef __attribute__((ext_vector_type(8))) _Float16 half8;
typedef __attribute__((ext_vector_type(4))) _Float16 half4;
typedef __attribute__((ext_vector_type(4))) float f32x4;

union HU { uint32_t u; _Float16 h[2]; };

// d_out float-index layout during the pipeline (per batch b, row r, col n at
// (b*256+r)*8192+n):
//   rows   0..127 : hA2 — h's interp contribution, fp16 x2 packed per u32
//                   (row cp holds channels 2cp, 2cp+1)
//   rows 128..191 : Gt_b = (W0[:,0:256] @ points2_b)^T, fp32 [s][o] (2 MB)
//   rows 192..255 : unused
// k_fused1 finally overwrites ALL of d_out with the fp32 output. Safety: by
// then Gt is dead, and each block clobbers hA2 only in its own columns, which
// it fully reads before any store (in-place trick).

// ---------------------------------------------------------------- top-3 NN
__global__ __launch_bounds__(256) void k_top3(const float* __restrict__ xyz1,
                                              const float* __restrict__ xyz2,
                                              uint32_t* __restrict__ pw3,
                                              float* __restrict__ psz) {
  __shared__ float md[4][3][64];
  __shared__ int mi[4][3][64];
  const int tid = threadIdx.x;
  if (blockIdx.x == 0 && blockIdx.y == 0) {  // zero BN partial-sum buffers
    psz[tid] = 0.f;
    psz[256 + tid] = 0.f;
  }
  const int wv = tid >> 6, lane = tid & 63;
  const int b = blockIdx.y;
  const int n = blockIdx.x * 64 + lane;
  const float* x1 = xyz1 + (size_t)b * 3 * N;
  const float ax = x1[n], ay = x1[n + N], az = x1[n + 2 * N];
  const float* x2 = xyz2 + (size_t)b * 3 * S;

  float d0 = 1e30f, d1 = 1e30f, d2 = 1e30f;
  int i0 = 0, i1 = 0, i2 = 0;
  const int s0 = wv * (S / 4), s1 = s0 + (S / 4);
#pragma unroll 8
  for (int s = s0; s < s1; ++s) {
    float sx = x2[s], sy = x2[s + S], sz = x2[s + 2 * S];  // wave-uniform
    float dx = ax - sx, dy = ay - sy, dz = az - sz;
    float d = dx * dx + dy * dy + dz * dz;
    if (d < d2) {  // strict < : stable (lowest index wins ties)
      if (d < d1) {
        d2 = d1; i2 = i1;
        if (d < d0) { d1 = d0; i1 = i0; d0 = d; i0 = s; }
        else        { d1 = d;  i1 = s; }
      } else { d2 = d; i2 = s; }
    }
  }
  md[wv][0][lane] = d0; mi[wv][0][lane] = i0;
  md[wv][1][lane] = d1; mi[wv][1][lane] = i1;
  md[wv][2][lane] = d2; mi[wv][2][lane] = i2;
  __syncthreads();
  if (tid < 64) {
    float e0 = md[0][0][tid], e1 = md[0][1][tid], e2 = md[0][2][tid];
    int j0 = mi[0][0][tid], j1 = mi[0][1][tid], j2 = mi[0][2][tid];
#pragma unroll
    for (int w = 1; w < 4; ++w)
#pragma unroll
      for (int k = 0; k < 3; ++k) {
        float d = md[w][k][tid];
        int i = mi[w][k][tid];
        if (d < e2) {  // ascending-s wave order + strict < = stable ties
          if (d < e1) {
            e2 = e1; j2 = j1;
            if (d < e0) { e1 = e0; j1 = j0; e0 = d; j0 = i; }
            else        { e1 = d;  j1 = i; }
          } else { e2 = d; j2 = i; }
        }
      }
    float r0 = 1.0f / (e0 + 1e-8f), r1 = 1.0f / (e1 + 1e-8f), r2 = 1.0f / (e2 + 1e-8f);
    float inv = 1.0f / (r0 + r1 + r2);
    auto pack = [](int i, float w) -> uint32_t {
      uint32_t q = (uint32_t)(w * 2097152.0f + 0.5f);
      if (q > 0x1FFFFFu) q = 0x1FFFFFu;
      return ((uint32_t)i << 21) | q;
    };
    size_t base = ((size_t)b * N + blockIdx.x * 64 + tid) * 3;
    pw3[base]     = pack(j0, r0 * inv);
    pw3[base + 1] = pack(j1, r1 * inv);
    pw3[base + 2] = pack(j2, r2 * inv);
  }
}

// ---------------------------- k_G: Gt_b[s][o] = (W0[:,0:256] @ points2_b)^T
// Block: 256 o-rows x 32 s-cols; transpose through LDS for coalesced stores.
__global__ __launch_bounds__(256) void k_G(const float* __restrict__ points2,
                                           const float* __restrict__ W0,
                                           float* __restrict__ dout) {
  __shared__ half8 A_lds[4][256];
  __shared__ half8 B_lds[4][32];
  __shared__ float CT[32][258];
  const int tid = threadIdx.x;
  const int b = blockIdx.x >> 6;
  const int s0 = (blockIdx.x & 63) * 32;
  f32x4 acc[4][2] = {};
  const int wv = tid >> 6, lane = tid & 63;
  const int ln = lane & 15, quad = lane >> 4;
  const int bn = tid & 31, bkc = tid >> 5;
  const int ar = tid >> 3, ac4 = tid & 7;

  for (int kk = 0; kk < 256; kk += 32) {
    __syncthreads();
#pragma unroll
    for (int p = 0; p < 8; ++p) {
      int row = ar + 32 * p;
      const float4 v = *(const float4*)(W0 + (size_t)row * CIN + kk + ac4 * 4);
      half4 hv = {(_Float16)v.x, (_Float16)v.y, (_Float16)v.z, (_Float16)v.w};
      *(half4*)((_Float16*)&A_lds[ac4 >> 1][row] + (ac4 & 1) * 4) = hv;
    }
    {
      half4 hv;
#pragma unroll
      for (int j = 0; j < 4; ++j)
        hv[j] = (_Float16)points2[((size_t)(b * 256 + kk + bkc * 4 + j)) * S + s0 + bn];
      *(half4*)((_Float16*)&B_lds[bkc >> 1][bn] + (bkc & 1) * 4) = hv;
    }
    __syncthreads();
    half8 af[4], bf[2];
#pragma unroll
    for (int i = 0; i < 4; ++i) af[i] = A_lds[quad][wv * 64 + i * 16 + ln];
#pragma unroll
    for (int j = 0; j < 2; ++j) bf[j] = B_lds[quad][j * 16 + ln];
#pragma unroll
    for (int i = 0; i < 4; ++i)
#pragma unroll
      for (int j = 0; j < 2; ++j)
        acc[i][j] = __builtin_amdgcn_mfma_f32_16x16x32_f16(af[i], bf[j], acc[i][j], 0, 0, 0);
  }
  __syncthreads();
#pragma unroll
  for (int i = 0; i < 4; ++i)
#pragma unroll
    for (int reg = 0; reg < 4; ++reg) {
      int row = wv * 64 + i * 16 + quad * 4 + reg;
#pragma unroll
      for (int j = 0; j < 2; ++j) CT[j * 16 + ln][row] = acc[i][j][reg];
    }
  __syncthreads();
  const int sl = tid >> 3, g = tid & 7;
  float* g0 = dout + ((size_t)(b * 256 + 128)) * 8192 + (size_t)(s0 + sl) * 256 + g * 32;
#pragma unroll
  for (int q = 0; q < 8; ++q)
    *(float4*)(g0 + q * 4) = *(const float4*)&CT[sl][g * 32 + q * 4];
}

// --------------- k_interp: hA2[b][cp][n] = pack(sum_k w_k * Gt_b[j_k][2cp..])
// Contiguous 1 KB reads per neighbor; writes packed fp16 pairs to rows 0..127.
__global__ __launch_bounds__(256) void k_interp(const uint32_t* __restrict__ pw3,
                                                const float* __restrict__ dout_c,
                                                uint32_t* __restrict__ dout_u) {
  __shared__ int sidx[96];
  __shared__ float sw[96];
  const int tid = threadIdx.x;
  const int b = blockIdx.x >> 8;
  const int n0 = (blockIdx.x & 255) * 32;
  if (tid < 96) {
    uint32_t p = pw3[((size_t)b * N + n0) * 3 + tid];
    sidx[tid] = (int)(p >> 21);
    sw[tid] = (float)(p & 0x1FFFFFu) * (1.0f / 2097152.0f);
  }
  __syncthreads();
  const int colL = tid >> 3, p = tid & 7;  // 8 lanes/col, 32 channels each
  const float* Gb = dout_c + ((size_t)(b * 256 + 128)) * 8192;
  float a[32];
#pragma unroll
  for (int q = 0; q < 32; ++q) a[q] = 0.f;
#pragma unroll
  for (int k = 0; k < 3; ++k) {
    int j = sidx[colL * 3 + k];
    float w = sw[colL * 3 + k];
    const float* g = Gb + (size_t)j * 256 + p * 32;
#pragma unroll
    for (int q = 0; q < 8; ++q) {
      float4 v = *(const float4*)(g + q * 4);
      a[q * 4 + 0] += w * v.x; a[q * 4 + 1] += w * v.y;
      a[q * 4 + 2] += w * v.z; a[q * 4 + 3] += w * v.w;
    }
  }
#pragma unroll
  for (int q = 0; q < 16; ++q) {
    int cp = p * 16 + q;
    HU u;
    u.h[0] = (_Float16)a[2 * q];
    u.h[1] = (_Float16)a[2 * q + 1];
    dout_u[((size_t)(b * 256 + cp)) * 8192 + n0 + colL] = u.u;
  }
}

// --------- k_stats: streaming BN stats of h = hA + W0[:,256:384]@p1 + b0.
// h never stored; per-channel sum/sumsq atomically accumulated into ws.
__global__ __launch_bounds__(256) void k_stats(const uint32_t* __restrict__ hA2,
                                               const float* __restrict__ points1,
                                               const float* __restrict__ W0,
                                               const float* __restrict__ b0,
                                               float* __restrict__ ps,
                                               float* __restrict__ ps2) {
  __shared__ half8 A_lds[4][256];
  __shared__ half8 B_lds[4][32];
  __shared__ float sb0[256];
  const int tid = threadIdx.x;
  const int b = blockIdx.x >> 8;
  const int n0 = (blockIdx.x & 255) * 32;
  sb0[tid] = b0[tid];
  f32x4 acc[4][2] = {};
  const int wv = tid >> 6, lane = tid & 63;
  const int ln = lane & 15, quad = lane >> 4;
  const int bn = tid & 31, bkc = tid >> 5;
  const int ar = tid >> 3, ac4 = tid & 7;

  for (int kk = 0; kk < 128; kk += 32) {
    __syncthreads();
#pragma unroll
    for (int p = 0; p < 8; ++p) {
      int row = ar + 32 * p;
      const float4 v = *(const float4*)(W0 + (size_t)row * CIN + 256 + kk + ac4 * 4);
      half4 hv = {(_Float16)v.x, (_Float16)v.y, (_Float16)v.z, (_Float16)v.w};
      *(half4*)((_Float16*)&A_lds[ac4 >> 1][row] + (ac4 & 1) * 4) = hv;
    }
    {
      half4 hv;
#pragma unroll
      for (int j = 0; j < 4; ++j)
        hv[j] = (_Float16)points1[((size_t)(b * D1 + kk + bkc * 4 + j)) * N + n0 + bn];
      *(half4*)((_Float16*)&B_lds[bkc >> 1][bn] + (bkc & 1) * 4) = hv;
    }
    __syncthreads();
    half8 af[4], bf[2];
#pragma unroll
    for (int i = 0; i < 4; ++i) af[i] = A_lds[quad][wv * 64 + i * 16 + ln];
#pragma unroll
    for (int j = 0; j < 2; ++j) bf[j] = B_lds[quad][j * 16 + ln];
#pragma unroll
    for (int i = 0; i < 4; ++i)
#pragma unroll
      for (int j = 0; j < 2; ++j)
        acc[i][j] = __builtin_amdgcn_mfma_f32_16x16x32_f16(af[i], bf[j], acc[i][j], 0, 0, 0);
  }
#pragma unroll
  for (int i = 0; i < 4; ++i) {
    const int rb = wv * 64 + i * 16 + quad * 4;
    const int cp0 = rb >> 1;
    float v[2][4];
#pragma unroll
    for (int j = 0; j < 2; ++j) {
      HU ua, ub;
      ua.u = hA2[((size_t)(b * 256 + cp0)) * 8192 + n0 + j * 16 + ln];
      ub.u = hA2[((size_t)(b * 256 + cp0 + 1)) * 8192 + n0 + j * 16 + ln];
      v[j][0] = acc[i][j][0] + (float)ua.h[0] + sb0[rb + 0];
      v[j][1] = acc[i][j][1] + (float)ua.h[1] + sb0[rb + 1];
      v[j][2] = acc[i][j][2] + (float)ub.h[0] + sb0[rb + 2];
      v[j][3] = acc[i][j][3] + (float)ub.h[1] + sb0[rb + 3];
    }
#pragma unroll
    for (int reg = 0; reg < 4; ++reg) {
      float s = v[0][reg] + v[1][reg];
      float q = v[0][reg] * v[0][reg] + v[1][reg] * v[1][reg];
#pragma unroll
      for (int m = 1; m < 16; m <<= 1) {
        s += __shfl_xor(s, m);
        q += __shfl_xor(q, m);
      }
      if (ln == 0) {
        atomicAdd(&ps[rb + reg], s);
        atomicAdd(&ps2[rb + reg], q);
      }
    }
  }
}

// -------------------------------------------------- BN finalize a,b per chan
__global__ __launch_bounds__(256) void k_bn(const float* __restrict__ ps,
                                            const float* __restrict__ ps2,
                                            const float* __restrict__ gamma,
                                            const float* __restrict__ beta,
                                            float* __restrict__ bna,
                                            float* __restrict__ bnb) {
  const int c = threadIdx.x;
  const float invn = 1.0f / (float)(B * N);
  float mean = ps[c] * invn;
  float var = ps2[c] * invn - mean * mean;  // biased, matches reference
  float a = gamma[c] * rsqrtf(var + 1e-5f);
  bna[c] = a;
  bnb[c] = beta[c] - mean * a;
}

// ------- k_fused1: out = relu(W1 @ relu(bn(hA + W0b@p1 + b0)) + b1), fp32.
// Phase 1 rebuilds the h tile in registers, bn+relu -> fp16 LDS (B-operand
// layout). Phase 2: W1 MFMA from LDS. Stores overwrite all of d_out; each
// block's hA2 reads (own columns only) complete before its stores.
__global__ __launch_bounds__(256) void k_fused1(const uint32_t* __restrict__ hA2,
                                                const float* __restrict__ points1,
                                                const float* __restrict__ W0,
                                                const float* __restrict__ b0,
                                                const float* __restrict__ W1,
                                                const float* __restrict__ b1,
                                                const float* __restrict__ bna,
                                                const float* __restrict__ bnb,
                                                float* __restrict__ out) {
  __shared__ half8 A_lds[4][256];
  __shared__ half8 B_lds[4][32];
  __shared__ _Float16 Hh[32][33][8];  // [k>>3][col][k&7], padded rows
  __shared__ float sa[256], sb[256], sb0[256], sb1[256];
  const int tid = threadIdx.x;
  const int b = blockIdx.x >> 8;
  const int n0 = (blockIdx.x & 255) * 32;
  sa[tid] = bna[tid]; sb[tid] = bnb[tid];
  sb0[tid] = b0[tid]; sb1[tid] = b1[tid];
  f32x4 acc[4][2] = {};
  const int wv = tid >> 6, lane = tid & 63;
  const int ln = lane & 15, quad = lane >> 4;
  const int bn = tid & 31, bkc = tid >> 5;
  const int ar = tid >> 3, ac4 = tid & 7;

  // phase 1: h tile = W0[:,256:384] @ p1 (+hA +b0), bn+relu -> Hh
  for (int kk = 0; kk < 128; kk += 32) {
    __syncthreads();
#pragma unroll
    for (int p = 0; p < 8; ++p) {
      int row = ar + 32 * p;
      const float4 v = *(const float4*)(W0 + (size_t)row * CIN + 256 + kk + ac4 * 4);
      half4 hv = {(_Float16)v.x, (_Float16)v.y, (_Float16)v.z, (_Float16)v.w};
      *(half4*)((_Float16*)&A_lds[ac4 >> 1][row] + (ac4 & 1) * 4) = hv;
    }
    {
      half4 hv;
#pragma unroll
      for (int j = 0; j < 4; ++j)
        hv[j] = (_Float16)points1[((size_t)(b * D1 + kk + bkc * 4 + j)) * N + n0 + bn];
      *(half4*)((_Float16*)&B_lds[bkc >> 1][bn] + (bkc & 1) * 4) = hv;
    }
    __syncthreads();
    half8 af[4], bf[2];
#pragma unroll
    for (int i = 0; i < 4; ++i) af[i] = A_lds[quad][wv * 64 + i * 16 + ln];
#pragma unroll
    for (int j = 0; j < 2; ++j) bf[j] = B_lds[quad][j * 16 + ln];
#pragma unroll
    for (int i = 0; i < 4; ++i)
#pragma unroll
      for (int j = 0; j < 2; ++j)
        acc[i][j] = __builtin_amdgcn_mfma_f32_16x16x32_f16(af[i], bf[j], acc[i][j], 0, 0, 0);
  }
#pragma unroll
  for (int i = 0; i < 4; ++i) {
    const int rb = wv * 64 + i * 16 + quad * 4;
    const int cp0 = rb >> 1;
#pragma unroll
    for (int j = 0; j < 2; ++j) {
      HU ua, ub;
      ua.u = hA2[((size_t)(b * 256 + cp0)) * 8192 + n0 + j * 16 + ln];
      ub.u = hA2[((size_t)(b * 256 + cp0 + 1)) * 8192 + n0 + j * 16 + ln];
      float hvals[4] = {(float)ua.h[0], (float)ua.h[1], (float)ub.h[0], (float)ub.h[1]};
      const int col = j * 16 + ln;
#pragma unroll
      for (int reg = 0; reg < 4; ++reg) {
        int row = rb + reg;
        float hv = acc[i][j][reg] + hvals[reg] + sb0[row];
        float vv = sa[row] * hv + sb[row];
        Hh[row >> 3][col][row & 7] = (_Float16)(vv > 0.f ? vv : 0.f);
      }
    }
  }
  // phase 2: out tile = W1 @ Hh
  f32x4 acc2[4][2] = {};
  for (int kk = 0; kk < 256; kk += 32) {
    __syncthreads();
#pragma unroll
    for (int p = 0; p < 8; ++p) {
      int row = ar + 32 * p;
      const float4 v = *(const float4*)(W1 + (size_t)row * CMID + kk + ac4 * 4);
      half4 hv = {(_Float16)v.x, (_Float16)v.y, (_Float16)v.z, (_Float16)v.w};
      *(half4*)((_Float16*)&A_lds[ac4 >> 1][row] + (ac4 & 1) * 4) = hv;
    }
    __syncthreads();
    half8 af[4], bf[2];
#pragma unroll
    for (int i = 0; i < 4; ++i) af[i] = A_lds[quad][wv * 64 + i * 16 + ln];
#pragma unroll
    for (int j = 0; j < 2; ++j)
      bf[j] = *(const half8*)&Hh[(kk >> 3) + quad][j * 16 + ln][0];
#pragma unroll
    for (int i = 0; i < 4; ++i)
#pragma unroll
      for (int j = 0; j < 2; ++j)
        acc2[i][j] = __builtin_amdgcn_mfma_f32_16x16x32_f16(af[i], bf[j], acc2[i][j], 0, 0, 0);
  }
#pragma unroll
  for (int i = 0; i < 4; ++i) {
    const int rb = wv * 64 + i * 16 + quad * 4;
#pragma unroll
    for (int reg = 0; reg < 4; ++reg) {
      int row = rb + reg;
      float bias = sb1[row];
      float* orow = out + ((size_t)(b * 256 + row)) * 8192 + n0;
#pragma unroll
      for (int j = 0; j < 2; ++j)
        orow[j * 16 + ln] = fmaxf(acc2[i][j][reg] + bias, 0.f);
    }
  }
}

extern "C" void kernel_launch(void* const* d_in, const int* in_sizes, int n_in,
                              void* d_out, int out_size, void* d_ws, size_t ws_size,
                              hipStream_t stream) {
  const float* xyz1 = (const float*)d_in[0];
  const float* xyz2 = (const float*)d_in[1];
  const float* points1 = (const float*)d_in[2];
  const float* points2 = (const float*)d_in[3];
  const float* W0 = (const float*)d_in[4];
  const float* b0 = (const float*)d_in[5];
  const float* gamma0 = (const float*)d_in[6];
  const float* beta0 = (const float*)d_in[7];
  const float* W1 = (const float*)d_in[8];
  const float* b1 = (const float*)d_in[9];
  float* out = (float*)d_out;

  // ws layout (772 KB; ws budget is ~1 MB — R0 overran at 1.57 MB):
  //   [0,1K) bna | [1K,2K) bnb | [2K,3K) ps | [3K,4K) ps2 | [4K,772K) pw3
  char* ws = (char*)d_ws;
  float* bna = (float*)ws;
  float* bnb = (float*)(ws + 1024);
  float* ps = (float*)(ws + 2048);
  float* ps2 = (float*)(ws + 3072);
  uint32_t* pw3 = (uint32_t*)(ws + 4096);

  k_top3<<<dim3(N / 64, B), 256, 0, stream>>>(xyz1, xyz2, pw3, ps);
  k_G<<<dim3(B * 64), 256, 0, stream>>>(points2, W0, out);
  k_interp<<<dim3(B * N / 32), 256, 0, stream>>>(pw3, out, (uint32_t*)out);
  k_stats<<<dim3(B * N / 32), 256, 0, stream>>>((const uint32_t*)out, points1, W0, b0, ps, ps2);
  k_bn<<<dim3(1), 256, 0, stream>>>(ps, ps2, gamma0, beta0, bna, bnb);
  k_fused1<<<dim3(B * N / 32), 256, 0, stream>>>((const uint32_t*)out, points1, W0, b0,
                                                 W1, b1, bna, bnb, out);
}

// Round 7
// 374.085 us; speedup vs baseline: 1.5767x; 1.5767x over previous
//
#include <hip/hip_runtime.h>
#include <stdint.h>

constexpr int B = 8, N = 8192, S = 2048, D1 = 128, D2 = 256;
constexpr int CIN = 384, CMID = 256, COUT = 256;

typedef __attribute__((ext_vector_type(8))) _Float16 half8;
typedef __attribute__((ext_vector_type(4))) _Float16 half4;
typedef __attribute__((ext_vector_type(4))) float f32x4;

union HU { uint32_t u; _Float16 h[2]; };

// d_out layout during the pipeline (float index (b*256+r)*8192+n):
//   rows   0..127 : hA2 (after k_interp) then h2 (after k_h) — fp16 x2 packed
//                   per u32; packed-row cp holds channels 2cp, 2cp+1
//   rows 128..191 : Gt_b = (W0[:,0:256] @ points2_b)^T, fp32 [s][o]
//   rows 192..199 : k_h per-block BN partial sums (sum[256], sumsq[256] per cb)
// k_fused1 finally overwrites ALL of d_out with fp32 output. Safe: Gt and
// partials are dead by then; each block fully reads its own h2 columns
// (pre-barrier) before storing.

// ---------------------------------------------------------------- top-3 NN
__global__ __launch_bounds__(256) void k_top3(const float* __restrict__ xyz1,
                                              const float* __restrict__ xyz2,
                                              uint32_t* __restrict__ pw3) {
  __shared__ float md[4][3][64];
  __shared__ int mi[4][3][64];
  const int tid = threadIdx.x;
  const int wv = tid >> 6, lane = tid & 63;
  const int b = blockIdx.y;
  const int n = blockIdx.x * 64 + lane;
  const float* x1 = xyz1 + (size_t)b * 3 * N;
  const float ax = x1[n], ay = x1[n + N], az = x1[n + 2 * N];
  const float* x2 = xyz2 + (size_t)b * 3 * S;

  float d0 = 1e30f, d1 = 1e30f, d2 = 1e30f;
  int i0 = 0, i1 = 0, i2 = 0;
  const int s0 = wv * (S / 4), s1 = s0 + (S / 4);
#pragma unroll 8
  for (int s = s0; s < s1; ++s) {
    float sx = x2[s], sy = x2[s + S], sz = x2[s + 2 * S];  // wave-uniform
    float dx = ax - sx, dy = ay - sy, dz = az - sz;
    float d = dx * dx + dy * dy + dz * dz;
    if (d < d2) {  // strict < : stable (lowest index wins ties)
      if (d < d1) {
        d2 = d1; i2 = i1;
        if (d < d0) { d1 = d0; i1 = i0; d0 = d; i0 = s; }
        else        { d1 = d;  i1 = s; }
      } else { d2 = d; i2 = s; }
    }
  }
  md[wv][0][lane] = d0; mi[wv][0][lane] = i0;
  md[wv][1][lane] = d1; mi[wv][1][lane] = i1;
  md[wv][2][lane] = d2; mi[wv][2][lane] = i2;
  __syncthreads();
  if (tid < 64) {
    float e0 = md[0][0][tid], e1 = md[0][1][tid], e2 = md[0][2][tid];
    int j0 = mi[0][0][tid], j1 = mi[0][1][tid], j2 = mi[0][2][tid];
#pragma unroll
    for (int w = 1; w < 4; ++w)
#pragma unroll
      for (int k = 0; k < 3; ++k) {
        float d = md[w][k][tid];
        int i = mi[w][k][tid];
        if (d < e2) {  // ascending-s wave order + strict < = stable ties
          if (d < e1) {
            e2 = e1; j2 = j1;
            if (d < e0) { e1 = e0; j1 = j0; e0 = d; j0 = i; }
            else        { e1 = d;  j1 = i; }
          } else { e2 = d; j2 = i; }
        }
      }
    float r0 = 1.0f / (e0 + 1e-8f), r1 = 1.0f / (e1 + 1e-8f), r2 = 1.0f / (e2 + 1e-8f);
    float inv = 1.0f / (r0 + r1 + r2);
    auto pack = [](int i, float w) -> uint32_t {
      uint32_t q = (uint32_t)(w * 2097152.0f + 0.5f);
      if (q > 0x1FFFFFu) q = 0x1FFFFFu;
      return ((uint32_t)i << 21) | q;
    };
    size_t base = ((size_t)b * N + blockIdx.x * 64 + tid) * 3;
    pw3[base]     = pack(j0, r0 * inv);
    pw3[base + 1] = pack(j1, r1 * inv);
    pw3[base + 2] = pack(j2, r2 * inv);
  }
}

// ---------------------------- k_G: Gt_b[s][o] = (W0[:,0:256] @ points2_b)^T
__global__ __launch_bounds__(256) void k_G(const float* __restrict__ points2,
                                           const float* __restrict__ W0,
                                           float* __restrict__ dout) {
  __shared__ half8 A_lds[4][256];
  __shared__ half8 B_lds[4][32];
  __shared__ float CT[32][258];
  const int tid = threadIdx.x;
  const int b = blockIdx.x >> 6;
  const int s0 = (blockIdx.x & 63) * 32;
  f32x4 acc[4][2] = {};
  const int wv = tid >> 6, lane = tid & 63;
  const int ln = lane & 15, quad = lane >> 4;
  const int bn = tid & 31, bkc = tid >> 5;
  const int ar = tid >> 3, ac4 = tid & 7;

  for (int kk = 0; kk < 256; kk += 32) {
    __syncthreads();
#pragma unroll
    for (int p = 0; p < 8; ++p) {
      int row = ar + 32 * p;
      const float4 v = *(const float4*)(W0 + (size_t)row * CIN + kk + ac4 * 4);
      half4 hv = {(_Float16)v.x, (_Float16)v.y, (_Float16)v.z, (_Float16)v.w};
      *(half4*)((_Float16*)&A_lds[ac4 >> 1][row] + (ac4 & 1) * 4) = hv;
    }
    {
      half4 hv;
#pragma unroll
      for (int j = 0; j < 4; ++j)
        hv[j] = (_Float16)points2[((size_t)(b * 256 + kk + bkc * 4 + j)) * S + s0 + bn];
      *(half4*)((_Float16*)&B_lds[bkc >> 1][bn] + (bkc & 1) * 4) = hv;
    }
    __syncthreads();
    half8 af[4], bf[2];
#pragma unroll
    for (int i = 0; i < 4; ++i) af[i] = A_lds[quad][wv * 64 + i * 16 + ln];
#pragma unroll
    for (int j = 0; j < 2; ++j) bf[j] = B_lds[quad][j * 16 + ln];
#pragma unroll
    for (int i = 0; i < 4; ++i)
#pragma unroll
      for (int j = 0; j < 2; ++j)
        acc[i][j] = __builtin_amdgcn_mfma_f32_16x16x32_f16(af[i], bf[j], acc[i][j], 0, 0, 0);
  }
  __syncthreads();
#pragma unroll
  for (int i = 0; i < 4; ++i)
#pragma unroll
    for (int reg = 0; reg < 4; ++reg) {
      int row = wv * 64 + i * 16 + quad * 4 + reg;
#pragma unroll
      for (int j = 0; j < 2; ++j) CT[j * 16 + ln][row] = acc[i][j][reg];
    }
  __syncthreads();
  const int sl = tid >> 3, g = tid & 7;
  float* g0 = dout + ((size_t)(b * 256 + 128)) * 8192 + (size_t)(s0 + sl) * 256 + g * 32;
#pragma unroll
  for (int q = 0; q < 8; ++q)
    *(float4*)(g0 + q * 4) = *(const float4*)&CT[sl][g * 32 + q * 4];
}

// --------------- k_interp: hA2[b][cp][n] = pack(sum_k w_k * Gt_b[j_k][2cp..])
__global__ __launch_bounds__(256) void k_interp(const uint32_t* __restrict__ pw3,
                                                const float* __restrict__ dout_c,
                                                uint32_t* __restrict__ dout_u) {
  __shared__ int sidx[96];
  __shared__ float sw[96];
  const int tid = threadIdx.x;
  const int b = blockIdx.x >> 8;
  const int n0 = (blockIdx.x & 255) * 32;
  if (tid < 96) {
    uint32_t p = pw3[((size_t)b * N + n0) * 3 + tid];
    sidx[tid] = (int)(p >> 21);
    sw[tid] = (float)(p & 0x1FFFFFu) * (1.0f / 2097152.0f);
  }
  __syncthreads();
  const int colL = tid >> 3, p = tid & 7;  // 8 lanes/col, 32 channels each
  const float* Gb = dout_c + ((size_t)(b * 256 + 128)) * 8192;
  float a[32];
#pragma unroll
  for (int q = 0; q < 32; ++q) a[q] = 0.f;
#pragma unroll
  for (int k = 0; k < 3; ++k) {
    int j = sidx[colL * 3 + k];
    float w = sw[colL * 3 + k];
    const float* g = Gb + (size_t)j * 256 + p * 32;
#pragma unroll
    for (int q = 0; q < 8; ++q) {
      float4 v = *(const float4*)(g + q * 4);
      a[q * 4 + 0] += w * v.x; a[q * 4 + 1] += w * v.y;
      a[q * 4 + 2] += w * v.z; a[q * 4 + 3] += w * v.w;
    }
  }
#pragma unroll
  for (int q = 0; q < 16; ++q) {
    int cp = p * 16 + q;
    HU u;
    u.h[0] = (_Float16)a[2 * q];
    u.h[1] = (_Float16)a[2 * q + 1];
    dout_u[((size_t)(b * 256 + cp)) * 8192 + n0 + colL] = u.u;
  }
}

// ------- k_h: h = hA + W0[:,256:384]@p1 + b0; write packed fp16 h2 in place
// over hA2; emit per-block BN partials (NO atomics) into d_out rows 192..199.
// 64-col tiles, 1024 blocks.
__global__ __launch_bounds__(256) void k_h(uint32_t* __restrict__ h2,
                                           float* __restrict__ dpart,
                                           const float* __restrict__ points1,
                                           const float* __restrict__ W0,
                                           const float* __restrict__ b0) {
  __shared__ half8 A_lds[4][256];  // 16 KB
  __shared__ half8 B_lds[4][64];   // 4 KB
  __shared__ float red_s[256], red_q[256], sb0[256];
  const int tid = threadIdx.x;
  const int b = blockIdx.x >> 7;
  const int cb = blockIdx.x & 127;
  const int n0 = cb * 64;
  sb0[tid] = b0[tid];
  f32x4 acc[4][4] = {};
  const int wv = tid >> 6, lane = tid & 63;
  const int ln = lane & 15, quad = lane >> 4;
  const int bn = tid & 63, bkc = tid >> 6;
  const int ar = tid >> 3, ac4 = tid & 7;

  for (int kk = 0; kk < 128; kk += 32) {
    __syncthreads();
#pragma unroll
    for (int p = 0; p < 8; ++p) {
      int row = ar + 32 * p;
      const float4 v = *(const float4*)(W0 + (size_t)row * CIN + 256 + kk + ac4 * 4);
      half4 hv = {(_Float16)v.x, (_Float16)v.y, (_Float16)v.z, (_Float16)v.w};
      *(half4*)((_Float16*)&A_lds[ac4 >> 1][row] + (ac4 & 1) * 4) = hv;
    }
    {
      half8 hv;
#pragma unroll
      for (int j = 0; j < 8; ++j)
        hv[j] = (_Float16)points1[((size_t)(b * D1 + kk + bkc * 8 + j)) * N + n0 + bn];
      B_lds[bkc][bn] = hv;
    }
    __syncthreads();
    half8 af[4], bf[4];
#pragma unroll
    for (int i = 0; i < 4; ++i) af[i] = A_lds[quad][wv * 64 + i * 16 + ln];
#pragma unroll
    for (int j = 0; j < 4; ++j) bf[j] = B_lds[quad][j * 16 + ln];
#pragma unroll
    for (int i = 0; i < 4; ++i)
#pragma unroll
      for (int j = 0; j < 4; ++j)
        acc[i][j] = __builtin_amdgcn_mfma_f32_16x16x32_f16(af[i], bf[j], acc[i][j], 0, 0, 0);
  }
  // epilogue: add hA + b0, round fp16, store in place, accumulate row sums
#pragma unroll
  for (int i = 0; i < 4; ++i) {
    const int rb = wv * 64 + i * 16 + quad * 4;
    const int cp0 = rb >> 1;
    float rs[4] = {0.f, 0.f, 0.f, 0.f}, rq[4] = {0.f, 0.f, 0.f, 0.f};
#pragma unroll
    for (int jj = 0; jj < 4; ++jj) {
      const int col = n0 + jj * 16 + ln;
      size_t a0 = ((size_t)(b * 256 + cp0)) * 8192 + col;
      HU ua, ub;
      ua.u = h2[a0];
      ub.u = h2[a0 + 8192];
      _Float16 e0 = (_Float16)(acc[i][jj][0] + (float)ua.h[0] + sb0[rb + 0]);
      _Float16 e1 = (_Float16)(acc[i][jj][1] + (float)ua.h[1] + sb0[rb + 1]);
      _Float16 e2 = (_Float16)(acc[i][jj][2] + (float)ub.h[0] + sb0[rb + 2]);
      _Float16 e3 = (_Float16)(acc[i][jj][3] + (float)ub.h[1] + sb0[rb + 3]);
      HU o0, o1;
      o0.h[0] = e0; o0.h[1] = e1; o1.h[0] = e2; o1.h[1] = e3;
      h2[a0] = o0.u;
      h2[a0 + 8192] = o1.u;
      float f0 = (float)e0, f1 = (float)e1, f2 = (float)e2, f3 = (float)e3;
      rs[0] += f0; rq[0] += f0 * f0;
      rs[1] += f1; rq[1] += f1 * f1;
      rs[2] += f2; rq[2] += f2 * f2;
      rs[3] += f3; rq[3] += f3 * f3;
    }
#pragma unroll
    for (int reg = 0; reg < 4; ++reg) {
      float s = rs[reg], q = rq[reg];
#pragma unroll
      for (int m = 1; m < 16; m <<= 1) {
        s += __shfl_xor(s, m);
        q += __shfl_xor(q, m);
      }
      if (ln == 0) { red_s[rb + reg] = s; red_q[rb + reg] = q; }
    }
  }
  __syncthreads();
  float* part = dpart + ((size_t)(b * 256 + 192)) * 8192 + (size_t)cb * 512;
  part[tid] = red_s[tid];
  part[256 + tid] = red_q[tid];
}

// ------------------------- k_bn: reduce 1024 partials/channel -> a,b per chan
__global__ __launch_bounds__(256) void k_bn(const float* __restrict__ dpart,
                                            const float* __restrict__ gamma,
                                            const float* __restrict__ beta,
                                            float* __restrict__ bna,
                                            float* __restrict__ bnb) {
  const int c = blockIdx.x;
  const int tid = threadIdx.x;
  float s = 0.f, q = 0.f;
#pragma unroll
  for (int u = tid; u < 1024; u += 256) {
    int b = u >> 7, cb = u & 127;
    const float* part = dpart + ((size_t)(b * 256 + 192)) * 8192 + (size_t)cb * 512;
    s += part[c];
    q += part[256 + c];
  }
#pragma unroll
  for (int m = 1; m < 64; m <<= 1) {
    s += __shfl_xor(s, m);
    q += __shfl_xor(q, m);
  }
  __shared__ float ls[4], lq[4];
  if ((tid & 63) == 0) { ls[tid >> 6] = s; lq[tid >> 6] = q; }
  __syncthreads();
  if (tid == 0) {
    float st = ls[0] + ls[1] + ls[2] + ls[3];
    float qt = lq[0] + lq[1] + lq[2] + lq[3];
    const float invn = 1.0f / (float)(B * N);
    float mean = st * invn;
    float var = qt * invn - mean * mean;  // biased, matches reference
    float a = gamma[c] * rsqrtf(var + 1e-5f);
    bna[c] = a;
    bnb[c] = beta[c] - mean * a;
  }
}

// ------- k_fused1: out = relu(W1 @ relu(a*h+b) + b1), fp32 over all of d_out.
// Phase 1: packed h2 -> BN affine+relu -> fp16 LDS. Phase 2: W1 fragments read
// DIRECTLY from global (L2-resident, no A_lds) -> sync-free MFMA K-loop.
// LDS 36 KB -> 4 blocks/CU.
__global__ __launch_bounds__(256) void k_fused1(const uint32_t* h2,
                                                const float* __restrict__ W1,
                                                const float* __restrict__ b1,
                                                const float* __restrict__ bna,
                                                const float* __restrict__ bnb,
                                                float* out) {
  __shared__ uint32_t Hh[32 * 65 * 4];  // [kc][col][k&7] halfs, col-padded
  __shared__ float sa[256], sb[256], sb1[256];
  const int tid = threadIdx.x;
  const int b = blockIdx.x >> 7;
  const int n0 = (blockIdx.x & 127) * 64;
  sa[tid] = bna[tid]; sb[tid] = bnb[tid]; sb1[tid] = b1[tid];
  __syncthreads();
  {
    const int col = tid & 63, cpb = tid >> 6;
#pragma unroll
    for (int q = 0; q < 32; ++q) {
      int cp = cpb * 32 + q;
      HU u;
      u.u = h2[((size_t)(b * 256 + cp)) * 8192 + n0 + col];
      int k0 = 2 * cp;
      float v0 = sa[k0] * (float)u.h[0] + sb[k0];
      float v1 = sa[k0 + 1] * (float)u.h[1] + sb[k0 + 1];
      HU o;
      o.h[0] = (_Float16)(v0 > 0.f ? v0 : 0.f);
      o.h[1] = (_Float16)(v1 > 0.f ? v1 : 0.f);
      Hh[((cp >> 2) * 65 + col) * 4 + (cp & 3)] = o.u;
    }
  }
  __syncthreads();
  f32x4 acc[4][4] = {};
  const int wv = tid >> 6, lane = tid & 63;
  const int ln = lane & 15, quad = lane >> 4;
  for (int kk = 0; kk < 256; kk += 32) {
    half8 af[4], bf[4];
#pragma unroll
    for (int i = 0; i < 4; ++i) {
      int row = wv * 64 + i * 16 + ln;
      const float* wr = W1 + (size_t)row * CMID + kk + quad * 8;
      float4 w0 = *(const float4*)wr;
      float4 w1v = *(const float4*)(wr + 4);
      af[i] = half8{(_Float16)w0.x, (_Float16)w0.y, (_Float16)w0.z, (_Float16)w0.w,
                    (_Float16)w1v.x, (_Float16)w1v.y, (_Float16)w1v.z, (_Float16)w1v.w};
    }
#pragma unroll
    for (int j = 0; j < 4; ++j)
      bf[j] = *(const half8*)&Hh[(((kk >> 3) + quad) * 65 + j * 16 + ln) * 4];
#pragma unroll
    for (int i = 0; i < 4; ++i)
#pragma unroll
      for (int j = 0; j < 4; ++j)
        acc[i][j] = __builtin_amdgcn_mfma_f32_16x16x32_f16(af[i], bf[j], acc[i][j], 0, 0, 0);
  }
#pragma unroll
  for (int i = 0; i < 4; ++i) {
    const int rb = wv * 64 + i * 16 + quad * 4;
#pragma unroll
    for (int reg = 0; reg < 4; ++reg) {
      int row = rb + reg;
      float bias = sb1[row];
      float* orow = out + ((size_t)(b * 256 + row)) * 8192 + n0;
#pragma unroll
      for (int j = 0; j < 4; ++j)
        orow[j * 16 + ln] = fmaxf(acc[i][j][reg] + bias, 0.f);
    }
  }
}

extern "C" void kernel_launch(void* const* d_in, const int* in_sizes, int n_in,
                              void* d_out, int out_size, void* d_ws, size_t ws_size,
                              hipStream_t stream) {
  const float* xyz1 = (const float*)d_in[0];
  const float* xyz2 = (const float*)d_in[1];
  const float* points1 = (const float*)d_in[2];
  const float* points2 = (const float*)d_in[3];
  const float* W0 = (const float*)d_in[4];
  const float* b0 = (const float*)d_in[5];
  const float* gamma0 = (const float*)d_in[6];
  const float* beta0 = (const float*)d_in[7];
  const float* W1 = (const float*)d_in[8];
  const float* b1 = (const float*)d_in[9];
  float* out = (float*)d_out;

  // ws layout (788,480 B == R1's proven-safe size; do NOT grow):
  //   [0,1K) bna | [1K,2K) bnb | [2K,770K) pw3
  char* ws = (char*)d_ws;
  float* bna = (float*)ws;
  float* bnb = (float*)(ws + 1024);
  uint32_t* pw3 = (uint32_t*)(ws + 2048);

  k_top3<<<dim3(N / 64, B), 256, 0, stream>>>(xyz1, xyz2, pw3);
  k_G<<<dim3(B * 64), 256, 0, stream>>>(points2, W0, out);
  k_interp<<<dim3(B * N / 32), 256, 0, stream>>>(pw3, out, (uint32_t*)out);
  k_h<<<dim3(B * N / 64), 256, 0, stream>>>((uint32_t*)out, out, points1, W0, b0);
  k_bn<<<dim3(256), 256, 0, stream>>>(out, gamma0, beta0, bna, bnb);
  k_fused1<<<dim3(B * N / 64), 256, 0, stream>>>((const uint32_t*)out, W1, b1,
                                                 bna, bnb, out);
}